// Round 2
// 502.680 us; speedup vs baseline: 1.1293x; 1.1293x over previous
//
#include <hip/hip_runtime.h>
#include <hip/hip_bf16.h>
#include <stdint.h>

#define DIM   1024
#define HID   2048
#define NE    8
#define TTOK  8192
#define BM    128
#define BN    128
#define BK    32
#define RMAX  (TTOK + NE * BM)   /* 9216 padded rows max */
#define MTMAX 72                 /* >= 8192/128 + 7 worst-case m-tiles */

typedef __attribute__((ext_vector_type(8))) short bf16x8;
typedef __attribute__((ext_vector_type(8))) unsigned short u16x8;
typedef __attribute__((ext_vector_type(4))) float f32x4;

// fp32 -> bf16 round-to-nearest-even on raw bits
__device__ inline unsigned short f2bf(float f) {
    union { float f; unsigned u; } v; v.f = f;
    unsigned r = v.u + 0x7fffu + ((v.u >> 16) & 1u);
    return (unsigned short)(r >> 16);
}

// async global->LDS, 16B per lane; lds base must be wave-uniform.
// NOTE (R3 lesson): keep the GLOBAL side quad-contiguous — the TA only
// merges consecutive-lane neighborhoods; scattered lane order 4x'd the
// request rate and cost 33% on gemm_up.
__device__ inline void async_copy16(const void* g, void* l) {
    __builtin_amdgcn_global_load_lds(
        (__attribute__((address_space(1))) void*)(void*)g,
        (__attribute__((address_space(3))) void*)l,
        16, 0, 0);
}

// ================= fused prep: route(+cnorm) and weight transposes =================
// One dispatch, roles striped by blockIdx%5 so HBM-bound transpose blocks
// overlap with L2/VALU-bound routing blocks (stream-serialized dispatches
// cannot overlap otherwise).

// ---- transpose body: W [Kd][Nd] fp32 -> Wt [Nd][Kd] bf16, tile 32n x 128k ----
// Reads: float4, 8 lanes/k-row => 128B contiguous read segments.
// LDS  : pitch 130 shorts => bank = (n + k/2) mod 32: conflict-free writes,
//        2-way (free) reads.
// Writes: u16x8, 8 lanes/n-row => 128B contiguous store segments (old kernel
//        had 64B segments — write-side coalescing was its bottleneck).
__device__ inline void transpose_body(const float* __restrict__ W,
                                      unsigned short* __restrict__ Wt,
                                      int Kd, int Nd, int e, int ntile, int ktile,
                                      unsigned short* tile /* [32*130] shorts */) {
    const float* src = W + (size_t)e * Kd * Nd;
    unsigned short* dst = Wt + (size_t)e * Kd * Nd;
    const int n0 = ntile * 32, k0 = ktile * 128;
    const int t = threadIdx.x;
    const int kr = t >> 3;             // 0..31
    const int nq = (t & 7) * 4;        // 0..28
#pragma unroll
    for (int p = 0; p < 4; ++p) {
        int k = p * 32 + kr;
        float4 v = *(const float4*)(src + (size_t)(k0 + k) * Nd + n0 + nq);
        tile[(nq + 0) * 130 + k] = f2bf(v.x);
        tile[(nq + 1) * 130 + k] = f2bf(v.y);
        tile[(nq + 2) * 130 + k] = f2bf(v.z);
        tile[(nq + 3) * 130 + k] = f2bf(v.w);
    }
    __syncthreads();
    const int r = t >> 3;              // n row 0..31
    const int c = t & 7;               // k chunk 0..7 (and c+8)
    u16x8 p0, p1;
#pragma unroll
    for (int kk = 0; kk < 8; ++kk) {
        p0[kk] = tile[r * 130 + c * 8 + kk];
        p1[kk] = tile[r * 130 + c * 8 + 64 + kk];
    }
    unsigned short* drow = dst + (size_t)(n0 + r) * Kd + k0 + c * 8;
    *(u16x8*)drow = p0;                // 16B-aligned (Kd, k0, c*8 all x8)
    *(u16x8*)(drow + 64) = p1;
}

// ---- route body: rmsnorm + argmin routing (fp32 exact) + bf16 xn write ----
// cnorm folded in: the block already loads every centroid for the dot
// products; cv.cv costs 4 FMA/e/thread and removes the cnorm_k dispatch.
__device__ inline void route_body(const float* __restrict__ x,
                                  const float* __restrict__ scale,
                                  const float* __restrict__ cent,
                                  int* __restrict__ ids,
                                  int* __restrict__ counts,
                                  unsigned short* __restrict__ xn,
                                  int tok, unsigned short* sm) {
    float* redf = (float*)sm;          // [4][17] partials + r at [68]
    const int tid = threadIdx.x;
    float4 xv = ((const float4*)(x + (size_t)tok * DIM))[tid];
    float4 sv = ((const float4*)scale)[tid];
    float4 xs; xs.x = xv.x * sv.x; xs.y = xv.y * sv.y; xs.z = xv.z * sv.z; xs.w = xv.w * sv.w;
    float vals[17];                    // [0]=ss, [1..8]=dot[e], [9..16]=cnorm[e]
    vals[0] = xv.x * xv.x + xv.y * xv.y + xv.z * xv.z + xv.w * xv.w;
#pragma unroll
    for (int e = 0; e < NE; ++e) {
        float4 cv = ((const float4*)(cent + (size_t)e * DIM))[tid];
        vals[1 + e] = xs.x * cv.x + xs.y * cv.y + xs.z * cv.z + xs.w * cv.w;
        vals[9 + e] = cv.x * cv.x + cv.y * cv.y + cv.z * cv.z + cv.w * cv.w;
    }
#pragma unroll
    for (int off = 32; off; off >>= 1) {
#pragma unroll
        for (int i = 0; i < 17; ++i) vals[i] += __shfl_down(vals[i], off);
    }
    const int w = tid >> 6, l = tid & 63;
    if (l == 0) {
#pragma unroll
        for (int i = 0; i < 17; ++i) redf[w * 17 + i] = vals[i];
    }
    __syncthreads();
    if (tid == 0) {
        float S = redf[0] + redf[17] + redf[34] + redf[51];
        float r = rsqrtf(S * (1.0f / DIM) + 1e-6f);
        float best = 3.4e38f; int be = 0;
#pragma unroll
        for (int e = 0; e < NE; ++e) {
            float D = redf[1 + e] + redf[17 + 1 + e] + redf[34 + 1 + e] + redf[51 + 1 + e];
            float C = redf[9 + e] + redf[17 + 9 + e] + redf[34 + 9 + e] + redf[51 + 9 + e];
            float dist = C - 2.0f * r * D;   // nx term dropped (argmin-invariant)
            if (dist < best) { best = dist; be = e; }
        }
        ids[tok] = be;
        atomicAdd(&counts[be], 1);
        redf[68] = r;
    }
    __syncthreads();
    float r = redf[68];
    ushort4 o;
    o.x = f2bf(xs.x * r); o.y = f2bf(xs.y * r);
    o.z = f2bf(xs.z * r); o.w = f2bf(xs.w * r);
    ((ushort4*)(xn + (size_t)tok * DIM))[tid] = o;
}

// Grid = 20480 blocks: stripes 0,1 -> up-transpose (8192), 2 -> down-transpose
// (4096), 3,4 -> route (8192). Striping interleaves HBM-bound and
// compute-bound blocks across the machine.
__global__ __launch_bounds__(256) void prep_k(const float* __restrict__ x,
                                              const float* __restrict__ scale,
                                              const float* __restrict__ cent,
                                              const float* __restrict__ up_w,
                                              const float* __restrict__ down_w,
                                              int* __restrict__ ids,
                                              int* __restrict__ counts,
                                              unsigned short* __restrict__ xn,
                                              unsigned short* __restrict__ upT,
                                              unsigned short* __restrict__ downT) {
    __shared__ __align__(16) unsigned short sm[32 * 130];
    int id = blockIdx.x;
    int q = id / 5;
    int s = id - q * 5;
    if (s < 2) {
        int u = q * 2 + s;                 // 0..8191: e(8) x ntile(128) x ktile(8)
        transpose_body(up_w, upT, DIM, 2 * HID, u >> 10, (u & 1023) >> 3, u & 7, sm);
    } else if (s == 2) {
        int v = q;                         // 0..4095: e(8) x ntile(32) x ktile(16)
        transpose_body(down_w, downT, HID, DIM, v >> 9, (v & 511) >> 4, v & 15, sm);
    } else {
        int tok = q * 2 + (s - 3);         // 0..8191
        route_body(x, scale, cent, ids, counts, xn, tok, sm);
    }
}

// ---------------- segment plan + tile map (1 block) ----------------
__global__ void plan_k(const int* __restrict__ counts, int* __restrict__ cursors,
                       int* __restrict__ tile_e, int* __restrict__ tile_row,
                       int* __restrict__ num_tiles) {
    if (threadIdx.x == 0) {
        int row = 0, nt = 0;
        for (int e = 0; e < NE; ++e) {
            cursors[e] = row;
            int c = counts[e];
            int tiles = (c + BM - 1) / BM;
            for (int i = 0; i < tiles; ++i) { tile_e[nt] = e; tile_row[nt] = row + i * BM; ++nt; }
            row += tiles * BM;
        }
        *num_tiles = nt;
    }
}

// ------- assign sorted slots (ballot-aggregated atomics: 1 per wave per expert) -------
__global__ __launch_bounds__(256) void place_k(const int* __restrict__ ids,
                                               int* __restrict__ cursors,
                                               int* __restrict__ sorted_tok) {
    int t = blockIdx.x * 256 + threadIdx.x;
    int e = ids[t];
    int lane = threadIdx.x & 63;
    int pos = 0;
#pragma unroll
    for (int ee = 0; ee < NE; ++ee) {
        unsigned long long grp = __ballot(e == ee);
        if (e == ee) {
            int leader = __ffsll((unsigned long long)grp) - 1;
            int base = 0;
            if (lane == leader) base = atomicAdd(&cursors[ee], (int)__popcll(grp));
            base = __shfl(base, leader);
            pos = base + (int)__popcll(grp & ((1ull << lane) - 1ull));
        }
    }
    sorted_tok[pos] = t;
}

// ---------------- up GEMM (dual tile: a & g) + fused swiglu ----------------
// Staging: lane l -> row (l>>2), chunk (l&3)*16B => quad-contiguous 64B global
// reads, row-major LDS (64B rows). Fragment ds_read_b128 has ~2% bank-conflict
// cost (measured R1: 6.7M cycles) — accepted, coalescing matters 15x more.
__global__ __launch_bounds__(256, 2) void gemm_up(const unsigned short* __restrict__ xn,
                                                  const unsigned short* __restrict__ upT,
                                                  unsigned short* __restrict__ act,
                                                  const int* __restrict__ sorted_tok,
                                                  const int* __restrict__ tile_e,
                                                  const int* __restrict__ tile_row,
                                                  const int* __restrict__ num_tiles) {
    int mt = blockIdx.x;
    if (mt >= *num_tiles) return;
    int n0 = blockIdx.y * BN;
    int e = tile_e[mt], row0 = tile_row[mt];

    __shared__ __align__(16) unsigned short As[BM * BK];
    __shared__ __align__(16) unsigned short Ba[BM * BK];
    __shared__ __align__(16) unsigned short Bg[BM * BK];

    const int tid = threadIdx.x;
    const int w = tid >> 6, l = tid & 63;
    const int rl = l & 15, q = l >> 4;
    const int m_off = (w >> 1) * 64, n_off = (w & 1) * 64;
    const int g0 = 2 * w, g1 = 2 * w + 1;

    const int sr = l >> 2;            // row within 16-row staging group
    const int sc = (l & 3) * 8;       // k-chunk (elements, 16B)

    // A rows indirect through sorted_tok (quad-contiguous 64B per token row);
    // pad rows (-1) clamp to 0 (dead data)
    int tok0 = sorted_tok[row0 + 16 * g0 + sr]; if (tok0 < 0) tok0 = 0;
    int tok1 = sorted_tok[row0 + 16 * g1 + sr]; if (tok1 < 0) tok1 = 0;
    const unsigned short* gA0 = xn + (size_t)tok0 * DIM + sc;
    const unsigned short* gA1 = xn + (size_t)tok1 * DIM + sc;
    const unsigned short* upE = upT + (size_t)e * (2 * HID) * DIM;
    const unsigned short* gBa0 = upE + (size_t)(n0 + 16 * g0 + sr) * DIM + sc;
    const unsigned short* gBa1 = upE + (size_t)(n0 + 16 * g1 + sr) * DIM + sc;
    const unsigned short* gBg0 = upE + (size_t)(HID + n0 + 16 * g0 + sr) * DIM + sc;
    const unsigned short* gBg1 = upE + (size_t)(HID + n0 + 16 * g1 + sr) * DIM + sc;

    unsigned short* lA0 = As + g0 * 512;  unsigned short* lA1 = As + g1 * 512;
    unsigned short* lBa0 = Ba + g0 * 512; unsigned short* lBa1 = Ba + g1 * 512;
    unsigned short* lBg0 = Bg + g0 * 512; unsigned short* lBg1 = Bg + g1 * 512;

    f32x4 accA[4][4], accG[4][4];
#pragma unroll
    for (int i = 0; i < 4; ++i)
#pragma unroll
        for (int j = 0; j < 4; ++j) {
            accA[i][j] = (f32x4){0.f, 0.f, 0.f, 0.f};
            accG[i][j] = (f32x4){0.f, 0.f, 0.f, 0.f};
        }

    const int NT = DIM / BK;
    for (int kt = 0; kt < NT; ++kt) {
        if (kt) __syncthreads();
        const int ko = kt * BK;
        async_copy16(gA0 + ko, lA0);
        async_copy16(gA1 + ko, lA1);
        async_copy16(gBa0 + ko, lBa0);
        async_copy16(gBa1 + ko, lBa1);
        async_copy16(gBg0 + ko, lBg0);
        async_copy16(gBg1 + ko, lBg1);
        __syncthreads();

        bf16x8 af[4], ba[4], bg[4];
#pragma unroll
        for (int mi = 0; mi < 4; ++mi)
            af[mi] = *(const bf16x8*)(As + (m_off + mi * 16 + rl) * BK + q * 8);
#pragma unroll
        for (int ni = 0; ni < 4; ++ni) {
            ba[ni] = *(const bf16x8*)(Ba + (n_off + ni * 16 + rl) * BK + q * 8);
            bg[ni] = *(const bf16x8*)(Bg + (n_off + ni * 16 + rl) * BK + q * 8);
        }
#pragma unroll
        for (int mi = 0; mi < 4; ++mi)
#pragma unroll
            for (int ni = 0; ni < 4; ++ni) {
                accA[mi][ni] = __builtin_amdgcn_mfma_f32_16x16x32_bf16(af[mi], ba[ni], accA[mi][ni], 0, 0, 0);
                accG[mi][ni] = __builtin_amdgcn_mfma_f32_16x16x32_bf16(af[mi], bg[ni], accG[mi][ni], 0, 0, 0);
            }
    }

    // epilogue: act = a * silu(g), bf16 (pad rows write garbage -> dead)
#pragma unroll
    for (int mi = 0; mi < 4; ++mi)
#pragma unroll
        for (int ni = 0; ni < 4; ++ni)
#pragma unroll
            for (int r = 0; r < 4; ++r) {
                float a = accA[mi][ni][r];
                float g = accG[mi][ni][r];
                float s = a * (g / (1.0f + __expf(-g)));
                int gr = row0 + m_off + mi * 16 + q * 4 + r;
                int gc = n0 + n_off + ni * 16 + rl;
                act[(size_t)gr * HID + gc] = f2bf(s);
            }
}

// ---------------- down GEMM + residual + scatter to d_out ----------------
__global__ __launch_bounds__(256, 2) void gemm_down(const unsigned short* __restrict__ act,
                                                    const unsigned short* __restrict__ downT,
                                                    const int* __restrict__ sorted_tok,
                                                    const float* __restrict__ x,
                                                    float* __restrict__ out,
                                                    const int* __restrict__ tile_e,
                                                    const int* __restrict__ tile_row,
                                                    const int* __restrict__ num_tiles) {
    int mt = blockIdx.x;
    if (mt >= *num_tiles) return;
    int n0 = blockIdx.y * BN;
    int e = tile_e[mt], row0 = tile_row[mt];

    __shared__ __align__(16) unsigned short As[BM * BK];
    __shared__ __align__(16) unsigned short Bs[BM * BK];

    const int tid = threadIdx.x;
    const int w = tid >> 6, l = tid & 63;
    const int rl = l & 15, q = l >> 4;
    const int m_off = (w >> 1) * 64, n_off = (w & 1) * 64;
    const int g0 = 2 * w, g1 = 2 * w + 1;

    const int sr = l >> 2;
    const int sc = (l & 3) * 8;

    const unsigned short* gA0 = act + (size_t)(row0 + 16 * g0 + sr) * HID + sc;
    const unsigned short* gA1 = act + (size_t)(row0 + 16 * g1 + sr) * HID + sc;
    const unsigned short* dnE = downT + (size_t)e * DIM * HID;
    const unsigned short* gB0 = dnE + (size_t)(n0 + 16 * g0 + sr) * HID + sc;
    const unsigned short* gB1 = dnE + (size_t)(n0 + 16 * g1 + sr) * HID + sc;

    unsigned short* lA0 = As + g0 * 512; unsigned short* lA1 = As + g1 * 512;
    unsigned short* lB0 = Bs + g0 * 512; unsigned short* lB1 = Bs + g1 * 512;

    f32x4 acc[4][4];
#pragma unroll
    for (int i = 0; i < 4; ++i)
#pragma unroll
        for (int j = 0; j < 4; ++j) acc[i][j] = (f32x4){0.f, 0.f, 0.f, 0.f};

    const int NT = HID / BK;
    for (int kt = 0; kt < NT; ++kt) {
        if (kt) __syncthreads();
        const int ko = kt * BK;
        async_copy16(gA0 + ko, lA0);
        async_copy16(gA1 + ko, lA1);
        async_copy16(gB0 + ko, lB0);
        async_copy16(gB1 + ko, lB1);
        __syncthreads();

        bf16x8 af[4], bf[4];
#pragma unroll
        for (int mi = 0; mi < 4; ++mi)
            af[mi] = *(const bf16x8*)(As + (m_off + mi * 16 + rl) * BK + q * 8);
#pragma unroll
        for (int ni = 0; ni < 4; ++ni)
            bf[ni] = *(const bf16x8*)(Bs + (n_off + ni * 16 + rl) * BK + q * 8);
#pragma unroll
        for (int mi = 0; mi < 4; ++mi)
#pragma unroll
            for (int ni = 0; ni < 4; ++ni)
                acc[mi][ni] = __builtin_amdgcn_mfma_f32_16x16x32_bf16(af[mi], bf[ni], acc[mi][ni], 0, 0, 0);
    }

    // epilogue: out[tok] = y + x[tok]; skip padding rows (tok = -1)
#pragma unroll
    for (int mi = 0; mi < 4; ++mi)
#pragma unroll
        for (int r = 0; r < 4; ++r) {
            int gr = row0 + m_off + mi * 16 + q * 4 + r;
            int tok = sorted_tok[gr];
            if (tok >= 0) {
#pragma unroll
                for (int ni = 0; ni < 4; ++ni) {
                    int gc = n0 + n_off + ni * 16 + rl;
                    size_t idx = (size_t)tok * DIM + gc;
                    out[idx] = acc[mi][ni][r] + x[idx];
                }
            }
        }
}

extern "C" void kernel_launch(void* const* d_in, const int* in_sizes, int n_in,
                              void* d_out, int out_size, void* d_ws, size_t ws_size,
                              hipStream_t stream) {
    const float* x      = (const float*)d_in[0];
    const float* scale  = (const float*)d_in[1];
    const float* cent   = (const float*)d_in[2];
    const float* up_w   = (const float*)d_in[3];
    const float* down_w = (const float*)d_in[4];
    float* out = (float*)d_out;
    char* ws = (char*)d_ws;

    // ---- workspace layout (bytes) ----
    int*   counts     = (int*)(ws + 0);      // 8
    int*   cursors    = (int*)(ws + 32);     // 8
    int*   num_tiles  = (int*)(ws + 96);     // 1
    int*   tile_e     = (int*)(ws + 128);    // MTMAX
    int*   tile_row   = (int*)(ws + 416);    // MTMAX
    int*   ids        = (int*)(ws + 1024);                   // TTOK
    int*   sorted_tok = (int*)(ws + 1024 + TTOK * 4);        // RMAX
    size_t off = 103424;                                     // 256-aligned
    unsigned short* xn    = (unsigned short*)(ws + off);     off += (size_t)TTOK * DIM * 2;
    unsigned short* act   = (unsigned short*)(ws + off);     off += (size_t)RMAX * HID * 2;
    unsigned short* upT   = (unsigned short*)(ws + off);     off += (size_t)NE * 2 * HID * DIM * 2;
    unsigned short* downT = (unsigned short*)(ws + off);     off += (size_t)NE * DIM * HID * 2;

    (void)hipMemsetAsync(ws, 0, 1024, stream);                        // counts/cursors/meta
    (void)hipMemsetAsync(sorted_tok, 0xFF, (size_t)RMAX * 4, stream); // pad rows = -1

    // fused: route(+cnorm) + both weight transposes in one overlapped dispatch
    prep_k<<<20480, 256, 0, stream>>>(x, scale, cent, up_w, down_w,
                                      ids, counts, xn, upT, downT);
    plan_k<<<1, 64, 0, stream>>>(counts, cursors, tile_e, tile_row, num_tiles);
    place_k<<<TTOK / 256, 256, 0, stream>>>(ids, cursors, sorted_tok);

    gemm_up<<<dim3(MTMAX, HID / BN), 256, 0, stream>>>(xn, upT, act, sorted_tok,
                                                       tile_e, tile_row, num_tiles);
    gemm_down<<<dim3(MTMAX, DIM / BN), 256, 0, stream>>>(act, downT, sorted_tok, x, out,
                                                         tile_e, tile_row, num_tiles);
}

// Round 3
// 488.553 us; speedup vs baseline: 1.1620x; 1.0289x over previous
//
#include <hip/hip_runtime.h>
#include <hip/hip_bf16.h>
#include <stdint.h>

#define DIM   1024
#define HID   2048
#define NE    8
#define TTOK  8192
#define BM    128
#define BN    128
#define BK    32
#define RMAX  (TTOK + NE * BM)   /* 9216 padded rows max */
#define MTMAX 72                 /* >= 8192/128 + 7 worst-case m-tiles */

typedef __attribute__((ext_vector_type(8))) short bf16x8;
typedef __attribute__((ext_vector_type(8))) unsigned short u16x8;
typedef __attribute__((ext_vector_type(4))) unsigned short u16x4;
typedef __attribute__((ext_vector_type(4))) float f32x4;

// fp32 -> bf16 round-to-nearest-even on raw bits
__device__ inline unsigned short f2bf(float f) {
    union { float f; unsigned u; } v; v.f = f;
    unsigned r = v.u + 0x7fffu + ((v.u >> 16) & 1u);
    return (unsigned short)(r >> 16);
}

// async global->LDS, 16B per lane; lds base must be wave-uniform.
// NOTE (R3 lesson): keep the GLOBAL side quad-contiguous — the TA only
// merges consecutive-lane neighborhoods; scattered lane order 4x'd the
// request rate and cost 33% on gemm_up.
__device__ inline void async_copy16(const void* g, void* l) {
    __builtin_amdgcn_global_load_lds(
        (__attribute__((address_space(1))) void*)(void*)g,
        (__attribute__((address_space(3))) void*)l,
        16, 0, 0);
}

// ---------------- centroid norms (tiny; token-invariant, so NOT in route) ----------------
__global__ __launch_bounds__(256) void cnorm_k(const float* __restrict__ cent,
                                               float* __restrict__ cnorm) {
    int e = blockIdx.x, tid = threadIdx.x;
    float4 cv = ((const float4*)(cent + (size_t)e * DIM))[tid];
    float ss = cv.x * cv.x + cv.y * cv.y + cv.z * cv.z + cv.w * cv.w;
#pragma unroll
    for (int off = 32; off; off >>= 1) ss += __shfl_down(ss, off);
    __shared__ float red[4];
    int w = tid >> 6, l = tid & 63;
    if (l == 0) red[w] = ss;
    __syncthreads();
    if (tid == 0) cnorm[e] = red[0] + red[1] + red[2] + red[3];
}

// ================= fused prep: route and weight transposes =================

// ---- transpose body: W [Kd][Nd] fp32 -> Wt [Nd][Kd] bf16, tile 64n x 128k ----
// Reads: float4, 16 lanes/k-row => 256B contiguous read segments; with
//        nt-fastest block ordering a resident cohort streams a contiguous
//        2MB source band (DRAM row locality — R2's 2TB/s was kt-fastest
//        128B-per-16KB-row scatter).
// LDS  : pitch 132 shorts (264B, 8B-aligned rows): writes ~4-way (1.58x,
//        accepted), b64 reads 2-way (free).
// Writes: u16x8 x4, 4 lanes/n-row => 256B contiguous store segments.
__device__ inline void transpose_body(const float* __restrict__ W,
                                      unsigned short* __restrict__ Wt,
                                      int Kd, int Nd, int e, int ntile, int ktile,
                                      unsigned short* tile /* [64*132] shorts */) {
    const float* src = W + (size_t)e * Kd * Nd;
    unsigned short* dst = Wt + (size_t)e * Kd * Nd;
    const int n0 = ntile * 64, k0 = ktile * 128;
    const int t = threadIdx.x;
    const int kr = t >> 4;             // 0..15
    const int nq = (t & 15) * 4;       // 0..60
#pragma unroll
    for (int p = 0; p < 8; ++p) {
        int k = p * 16 + kr;
        float4 v = *(const float4*)(src + (size_t)(k0 + k) * Nd + n0 + nq);
        tile[(nq + 0) * 132 + k] = f2bf(v.x);
        tile[(nq + 1) * 132 + k] = f2bf(v.y);
        tile[(nq + 2) * 132 + k] = f2bf(v.z);
        tile[(nq + 3) * 132 + k] = f2bf(v.w);
    }
    __syncthreads();
    const int r = t >> 2;              // n row 0..63
    const int c = t & 3;               // 32-short k chunk 0..3
    const unsigned short* bsrc = tile + r * 132 + c * 32;
    u16x4 a0 = *(const u16x4*)(bsrc + 0);
    u16x4 a1 = *(const u16x4*)(bsrc + 4);
    u16x4 a2 = *(const u16x4*)(bsrc + 8);
    u16x4 a3 = *(const u16x4*)(bsrc + 12);
    u16x4 a4 = *(const u16x4*)(bsrc + 16);
    u16x4 a5 = *(const u16x4*)(bsrc + 20);
    u16x4 a6 = *(const u16x4*)(bsrc + 24);
    u16x4 a7 = *(const u16x4*)(bsrc + 28);
    u16x8 s0, s1, s2, s3;
#pragma unroll
    for (int i = 0; i < 4; ++i) {
        s0[i] = a0[i]; s0[4 + i] = a1[i];
        s1[i] = a2[i]; s1[4 + i] = a3[i];
        s2[i] = a4[i]; s2[4 + i] = a5[i];
        s3[i] = a6[i]; s3[4 + i] = a7[i];
    }
    unsigned short* drow = dst + (size_t)(n0 + r) * Kd + k0 + c * 32;
    *(u16x8*)(drow + 0)  = s0;         // 64B-aligned
    *(u16x8*)(drow + 8)  = s1;
    *(u16x8*)(drow + 16) = s2;
    *(u16x8*)(drow + 24) = s3;
}

// ---- route body: rmsnorm + argmin routing (fp32 exact) + bf16 xn write ----
// 9-value butterfly (ss + 8 dots); cnorm read from cnorm_k's output — folding
// it in cost 48 extra ds_bpermute/thread across 8192 blocks (R2 lesson).
__device__ inline void route_body(const float* __restrict__ x,
                                  const float* __restrict__ scale,
                                  const float* __restrict__ cent,
                                  const float* __restrict__ cnorm,
                                  int* __restrict__ ids,
                                  int* __restrict__ counts,
                                  unsigned short* __restrict__ xn,
                                  int tok, unsigned short* sm) {
    float* redf = (float*)sm;          // [4][10] partials + r at [40]
    const int tid = threadIdx.x;
    float4 xv = ((const float4*)(x + (size_t)tok * DIM))[tid];
    float4 sv = ((const float4*)scale)[tid];
    float4 xs; xs.x = xv.x * sv.x; xs.y = xv.y * sv.y; xs.z = xv.z * sv.z; xs.w = xv.w * sv.w;
    float vals[9];                     // [0]=ss, [1..8]=dot[e]
    vals[0] = xv.x * xv.x + xv.y * xv.y + xv.z * xv.z + xv.w * xv.w;
#pragma unroll
    for (int e = 0; e < NE; ++e) {
        float4 cv = ((const float4*)(cent + (size_t)e * DIM))[tid];
        vals[1 + e] = xs.x * cv.x + xs.y * cv.y + xs.z * cv.z + xs.w * cv.w;
    }
#pragma unroll
    for (int off = 32; off; off >>= 1) {
#pragma unroll
        for (int i = 0; i < 9; ++i) vals[i] += __shfl_down(vals[i], off);
    }
    const int w = tid >> 6, l = tid & 63;
    if (l == 0) {
#pragma unroll
        for (int i = 0; i < 9; ++i) redf[w * 10 + i] = vals[i];
    }
    __syncthreads();
    if (tid == 0) {
        float S = redf[0] + redf[10] + redf[20] + redf[30];
        float r = rsqrtf(S * (1.0f / DIM) + 1e-6f);
        float best = 3.4e38f; int be = 0;
#pragma unroll
        for (int e = 0; e < NE; ++e) {
            float D = redf[1 + e] + redf[10 + 1 + e] + redf[20 + 1 + e] + redf[30 + 1 + e];
            float dist = cnorm[e] - 2.0f * r * D;   // nx term dropped (argmin-invariant)
            if (dist < best) { best = dist; be = e; }
        }
        ids[tok] = be;
        atomicAdd(&counts[be], 1);
        redf[40] = r;
    }
    __syncthreads();
    float r = redf[40];
    ushort4 o;
    o.x = f2bf(xs.x * r); o.y = f2bf(xs.y * r);
    o.z = f2bf(xs.z * r); o.w = f2bf(xs.w * r);
    ((ushort4*)(xn + (size_t)tok * DIM))[tid] = o;
}

// Grid = 2048*7 blocks: stripes 0..2 -> transposes (6144: 4096 up + 2048 down,
// nt-fastest within each), stripes 3..6 -> route (8192). Striping interleaves
// HBM-bound and LDS/VALU-bound blocks across the machine.
__global__ __launch_bounds__(256) void prep_k(const float* __restrict__ x,
                                              const float* __restrict__ scale,
                                              const float* __restrict__ cent,
                                              const float* __restrict__ cnorm,
                                              const float* __restrict__ up_w,
                                              const float* __restrict__ down_w,
                                              int* __restrict__ ids,
                                              int* __restrict__ counts,
                                              unsigned short* __restrict__ xn,
                                              unsigned short* __restrict__ upT,
                                              unsigned short* __restrict__ downT) {
    __shared__ __align__(16) unsigned short sm[64 * 132];
    int id = blockIdx.x;
    int q = id / 7;
    int s = id - q * 7;
    if (s < 3) {
        int v = q * 3 + s;                 // 0..6143
        if (v < 4096) {                    // up: e(8) x kt(8) x nt(64), nt fastest
            int rem = v & 511;
            transpose_body(up_w, upT, DIM, 2 * HID, v >> 9, rem & 63, rem >> 6, sm);
        } else {                           // down: e(8) x kt(16) x nt(16), nt fastest
            int wdn = v - 4096;
            int rem = wdn & 255;
            transpose_body(down_w, downT, HID, DIM, wdn >> 8, rem & 15, rem >> 4, sm);
        }
    } else {
        int tok = q * 4 + (s - 3);         // 0..8191
        route_body(x, scale, cent, cnorm, ids, counts, xn, tok, sm);
    }
}

// ------- assign sorted slots; plan recomputed inline from counts -------
// (plan_k dispatch eliminated; segment bases are a trivial 8-expert prefix.)
// Block 0 also fills pad rows with -1 (disjoint addresses from real slots,
// so no intra-dispatch ordering needed) — replaces the 37KB memset dispatch.
__global__ __launch_bounds__(256) void place_k(const int* __restrict__ ids,
                                               const int* __restrict__ counts,
                                               int* __restrict__ cursors,
                                               int* __restrict__ sorted_tok) {
    int tid = threadIdx.x;
    int t = blockIdx.x * 256 + tid;
    int e = ids[t];
    int base = 0;
    {
        int row = 0;
#pragma unroll
        for (int ee = 0; ee < NE; ++ee) {
            if (ee == e) base = row;
            row += (counts[ee] + BM - 1) & ~(BM - 1);
        }
    }
    int lane = tid & 63;
    int pos = 0;
#pragma unroll
    for (int ee = 0; ee < NE; ++ee) {
        unsigned long long grp = __ballot(e == ee);
        if (e == ee) {
            int leader = __ffsll((unsigned long long)grp) - 1;
            int off = 0;
            if (lane == leader) off = atomicAdd(&cursors[ee], (int)__popcll(grp));
            off = __shfl(off, leader);
            pos = base + off + (int)__popcll(grp & ((1ull << lane) - 1ull));
        }
    }
    sorted_tok[pos] = t;
    if (blockIdx.x == 0) {
        int row = 0;
#pragma unroll
        for (int ee = 0; ee < NE; ++ee) {
            int c = counts[ee];
            int seg = (c + BM - 1) & ~(BM - 1);
            for (int i = c + tid; i < seg; i += 256) sorted_tok[row + i] = -1;
            row += seg;
        }
    }
}

// Inline tile map: recompute (e, row0) for tile mt from counts (~30 scalar
// ops, wave-uniform). Returns false for out-of-range mt.
__device__ inline bool tile_map(const int* __restrict__ counts, int mt,
                                int& e, int& row0) {
    int4 c0 = ((const int4*)counts)[0];
    int4 c1 = ((const int4*)counts)[1];
    int cc[8] = {c0.x, c0.y, c0.z, c0.w, c1.x, c1.y, c1.z, c1.w};
    e = -1; row0 = 0;
    int acc = 0, row = 0;
#pragma unroll
    for (int ee = 0; ee < NE; ++ee) {
        int tiles = (cc[ee] + BM - 1) >> 7;
        if (e < 0 && mt < acc + tiles) { e = ee; row0 = row + (mt - acc) * BM; }
        acc += tiles; row += tiles * BM;
    }
    return e >= 0;
}

// ---------------- up GEMM (dual tile: a & g) + fused swiglu ----------------
// Staging: lane l -> row (l>>2), chunk (l&3)*16B => quad-contiguous 64B global
// reads, row-major LDS (64B rows). Fragment ds_read_b128 has ~2% bank-conflict
// cost (measured R1: 6.7M cycles) — accepted, coalescing matters 15x more.
__global__ __launch_bounds__(256, 2) void gemm_up(const unsigned short* __restrict__ xn,
                                                  const unsigned short* __restrict__ upT,
                                                  unsigned short* __restrict__ act,
                                                  const int* __restrict__ sorted_tok,
                                                  const int* __restrict__ counts) {
    int e, row0;
    if (!tile_map(counts, blockIdx.x, e, row0)) return;
    int n0 = blockIdx.y * BN;

    __shared__ __align__(16) unsigned short As[BM * BK];
    __shared__ __align__(16) unsigned short Ba[BM * BK];
    __shared__ __align__(16) unsigned short Bg[BM * BK];

    const int tid = threadIdx.x;
    const int w = tid >> 6, l = tid & 63;
    const int rl = l & 15, q = l >> 4;
    const int m_off = (w >> 1) * 64, n_off = (w & 1) * 64;
    const int g0 = 2 * w, g1 = 2 * w + 1;

    const int sr = l >> 2;            // row within 16-row staging group
    const int sc = (l & 3) * 8;       // k-chunk (elements, 16B)

    // A rows indirect through sorted_tok (quad-contiguous 64B per token row);
    // pad rows (-1) clamp to 0 (dead data)
    int tok0 = sorted_tok[row0 + 16 * g0 + sr]; if (tok0 < 0) tok0 = 0;
    int tok1 = sorted_tok[row0 + 16 * g1 + sr]; if (tok1 < 0) tok1 = 0;
    const unsigned short* gA0 = xn + (size_t)tok0 * DIM + sc;
    const unsigned short* gA1 = xn + (size_t)tok1 * DIM + sc;
    const unsigned short* upE = upT + (size_t)e * (2 * HID) * DIM;
    const unsigned short* gBa0 = upE + (size_t)(n0 + 16 * g0 + sr) * DIM + sc;
    const unsigned short* gBa1 = upE + (size_t)(n0 + 16 * g1 + sr) * DIM + sc;
    const unsigned short* gBg0 = upE + (size_t)(HID + n0 + 16 * g0 + sr) * DIM + sc;
    const unsigned short* gBg1 = upE + (size_t)(HID + n0 + 16 * g1 + sr) * DIM + sc;

    unsigned short* lA0 = As + g0 * 512;  unsigned short* lA1 = As + g1 * 512;
    unsigned short* lBa0 = Ba + g0 * 512; unsigned short* lBa1 = Ba + g1 * 512;
    unsigned short* lBg0 = Bg + g0 * 512; unsigned short* lBg1 = Bg + g1 * 512;

    f32x4 accA[4][4], accG[4][4];
#pragma unroll
    for (int i = 0; i < 4; ++i)
#pragma unroll
        for (int j = 0; j < 4; ++j) {
            accA[i][j] = (f32x4){0.f, 0.f, 0.f, 0.f};
            accG[i][j] = (f32x4){0.f, 0.f, 0.f, 0.f};
        }

    const int NT = DIM / BK;
    for (int kt = 0; kt < NT; ++kt) {
        if (kt) __syncthreads();
        const int ko = kt * BK;
        async_copy16(gA0 + ko, lA0);
        async_copy16(gA1 + ko, lA1);
        async_copy16(gBa0 + ko, lBa0);
        async_copy16(gBa1 + ko, lBa1);
        async_copy16(gBg0 + ko, lBg0);
        async_copy16(gBg1 + ko, lBg1);
        __syncthreads();

        bf16x8 af[4], ba[4], bg[4];
#pragma unroll
        for (int mi = 0; mi < 4; ++mi)
            af[mi] = *(const bf16x8*)(As + (m_off + mi * 16 + rl) * BK + q * 8);
#pragma unroll
        for (int ni = 0; ni < 4; ++ni) {
            ba[ni] = *(const bf16x8*)(Ba + (n_off + ni * 16 + rl) * BK + q * 8);
            bg[ni] = *(const bf16x8*)(Bg + (n_off + ni * 16 + rl) * BK + q * 8);
        }
#pragma unroll
        for (int mi = 0; mi < 4; ++mi)
#pragma unroll
            for (int ni = 0; ni < 4; ++ni) {
                accA[mi][ni] = __builtin_amdgcn_mfma_f32_16x16x32_bf16(af[mi], ba[ni], accA[mi][ni], 0, 0, 0);
                accG[mi][ni] = __builtin_amdgcn_mfma_f32_16x16x32_bf16(af[mi], bg[ni], accG[mi][ni], 0, 0, 0);
            }
    }

    // epilogue: act = a * silu(g), bf16 (pad rows write garbage -> dead)
#pragma unroll
    for (int mi = 0; mi < 4; ++mi)
#pragma unroll
        for (int ni = 0; ni < 4; ++ni)
#pragma unroll
            for (int r = 0; r < 4; ++r) {
                float a = accA[mi][ni][r];
                float g = accG[mi][ni][r];
                float s = a * (g / (1.0f + __expf(-g)));
                int gr = row0 + m_off + mi * 16 + q * 4 + r;
                int gc = n0 + n_off + ni * 16 + rl;
                act[(size_t)gr * HID + gc] = f2bf(s);
            }
}

// ---------------- down GEMM + residual + scatter to d_out ----------------
__global__ __launch_bounds__(256, 2) void gemm_down(const unsigned short* __restrict__ act,
                                                    const unsigned short* __restrict__ downT,
                                                    const int* __restrict__ sorted_tok,
                                                    const int* __restrict__ counts,
                                                    const float* __restrict__ x,
                                                    float* __restrict__ out) {
    int e, row0;
    if (!tile_map(counts, blockIdx.x, e, row0)) return;
    int n0 = blockIdx.y * BN;

    __shared__ __align__(16) unsigned short As[BM * BK];
    __shared__ __align__(16) unsigned short Bs[BM * BK];

    const int tid = threadIdx.x;
    const int w = tid >> 6, l = tid & 63;
    const int rl = l & 15, q = l >> 4;
    const int m_off = (w >> 1) * 64, n_off = (w & 1) * 64;
    const int g0 = 2 * w, g1 = 2 * w + 1;

    const int sr = l >> 2;
    const int sc = (l & 3) * 8;

    const unsigned short* gA0 = act + (size_t)(row0 + 16 * g0 + sr) * HID + sc;
    const unsigned short* gA1 = act + (size_t)(row0 + 16 * g1 + sr) * HID + sc;
    const unsigned short* dnE = downT + (size_t)e * DIM * HID;
    const unsigned short* gB0 = dnE + (size_t)(n0 + 16 * g0 + sr) * HID + sc;
    const unsigned short* gB1 = dnE + (size_t)(n0 + 16 * g1 + sr) * HID + sc;

    unsigned short* lA0 = As + g0 * 512; unsigned short* lA1 = As + g1 * 512;
    unsigned short* lB0 = Bs + g0 * 512; unsigned short* lB1 = Bs + g1 * 512;

    f32x4 acc[4][4];
#pragma unroll
    for (int i = 0; i < 4; ++i)
#pragma unroll
        for (int j = 0; j < 4; ++j) acc[i][j] = (f32x4){0.f, 0.f, 0.f, 0.f};

    const int NT = HID / BK;
    for (int kt = 0; kt < NT; ++kt) {
        if (kt) __syncthreads();
        const int ko = kt * BK;
        async_copy16(gA0 + ko, lA0);
        async_copy16(gA1 + ko, lA1);
        async_copy16(gB0 + ko, lB0);
        async_copy16(gB1 + ko, lB1);
        __syncthreads();

        bf16x8 af[4], bf[4];
#pragma unroll
        for (int mi = 0; mi < 4; ++mi)
            af[mi] = *(const bf16x8*)(As + (m_off + mi * 16 + rl) * BK + q * 8);
#pragma unroll
        for (int ni = 0; ni < 4; ++ni)
            bf[ni] = *(const bf16x8*)(Bs + (n_off + ni * 16 + rl) * BK + q * 8);
#pragma unroll
        for (int mi = 0; mi < 4; ++mi)
#pragma unroll
            for (int ni = 0; ni < 4; ++ni)
                acc[mi][ni] = __builtin_amdgcn_mfma_f32_16x16x32_bf16(af[mi], bf[ni], acc[mi][ni], 0, 0, 0);
    }

    // epilogue: out[tok] = y + x[tok]; skip padding rows (tok = -1)
#pragma unroll
    for (int mi = 0; mi < 4; ++mi)
#pragma unroll
        for (int r = 0; r < 4; ++r) {
            int gr = row0 + m_off + mi * 16 + q * 4 + r;
            int tok = sorted_tok[gr];
            if (tok >= 0) {
#pragma unroll
                for (int ni = 0; ni < 4; ++ni) {
                    int gc = n0 + n_off + ni * 16 + rl;
                    size_t idx = (size_t)tok * DIM + gc;
                    out[idx] = acc[mi][ni][r] + x[idx];
                }
            }
        }
}

extern "C" void kernel_launch(void* const* d_in, const int* in_sizes, int n_in,
                              void* d_out, int out_size, void* d_ws, size_t ws_size,
                              hipStream_t stream) {
    const float* x      = (const float*)d_in[0];
    const float* scale  = (const float*)d_in[1];
    const float* cent   = (const float*)d_in[2];
    const float* up_w   = (const float*)d_in[3];
    const float* down_w = (const float*)d_in[4];
    float* out = (float*)d_out;
    char* ws = (char*)d_ws;

    // ---- workspace layout (bytes) ----
    int*   counts     = (int*)(ws + 0);      // 8
    int*   cursors    = (int*)(ws + 32);     // 8
    float* cnorm      = (float*)(ws + 704);  // 8
    int*   ids        = (int*)(ws + 1024);                   // TTOK
    int*   sorted_tok = (int*)(ws + 1024 + TTOK * 4);        // RMAX
    size_t off = 103424;                                     // 256-aligned
    unsigned short* xn    = (unsigned short*)(ws + off);     off += (size_t)TTOK * DIM * 2;
    unsigned short* act   = (unsigned short*)(ws + off);     off += (size_t)RMAX * HID * 2;
    unsigned short* upT   = (unsigned short*)(ws + off);     off += (size_t)NE * 2 * HID * DIM * 2;
    unsigned short* downT = (unsigned short*)(ws + off);     off += (size_t)NE * DIM * HID * 2;

    (void)hipMemsetAsync(ws, 0, 1024, stream);   // counts/cursors/meta

    cnorm_k<<<NE, 256, 0, stream>>>(cent, cnorm);
    prep_k<<<2048 * 7, 256, 0, stream>>>(x, scale, cent, cnorm, up_w, down_w,
                                         ids, counts, xn, upT, downT);
    place_k<<<TTOK / 256, 256, 0, stream>>>(ids, counts, cursors, sorted_tok);

    gemm_up<<<dim3(MTMAX, HID / BN), 256, 0, stream>>>(xn, upT, act, sorted_tok, counts);
    gemm_down<<<dim3(MTMAX, DIM / BN), 256, 0, stream>>>(act, downT, sorted_tok, counts, x, out);
}